// Round 2
// baseline (1767.177 us; speedup 1.0000x reference)
//
#include <hip/hip_runtime.h>
#include <hip/hip_bf16.h>

// GraphAutoEncoder: out = adj@(h@W_dec), h = adj@(x@W_enc), h_a = adj@((x@W_enc)[perm])
// Rewrites: out = (adj@h)@W_dec  (associativity);  x[perm]@W_enc = z1[perm].
// Edges counting-sorted by row once; SpMMs are then atomic-free.

#define THREADS 256

// ---------------- utility kernels ----------------

__global__ void zero_i32(int* __restrict__ p, int n) {
    int i = blockIdx.x * blockDim.x + threadIdx.x;
    if (i < n) p[i] = 0;
}

__global__ void copy_i32(const int* __restrict__ src, int* __restrict__ dst, int n) {
    int i = blockIdx.x * blockDim.x + threadIdx.x;
    if (i < n) dst[i] = src[i];
}

__global__ void hist_rows(const int* __restrict__ row, int* __restrict__ cnt, int E) {
    for (int e = blockIdx.x * blockDim.x + threadIdx.x; e < E; e += gridDim.x * blockDim.x)
        atomicAdd(&cnt[row[e]], 1);
}

// chunk = 1024 elements per block (256 threads x 4)
__global__ void scan_partial(const int* __restrict__ cnt, int* __restrict__ bsum, int n) {
    __shared__ int red[256];
    int t = threadIdx.x;
    int base = blockIdx.x * 1024 + t * 4;
    int s = 0;
#pragma unroll
    for (int i = 0; i < 4; ++i) {
        int idx = base + i;
        if (idx < n) s += cnt[idx];
    }
    red[t] = s;
    __syncthreads();
    for (int off = 128; off > 0; off >>= 1) {
        if (t < off) red[t] += red[t + off];
        __syncthreads();
    }
    if (t == 0) bsum[blockIdx.x] = red[0];
}

// single block, 128 threads; nb <= 128
__global__ void scan_bsum(const int* __restrict__ bsum, int* __restrict__ bscan,
                          int nb, int* __restrict__ rowptr, int n, int E) {
    __shared__ int s[128];
    int t = threadIdx.x;
    int v = (t < nb) ? bsum[t] : 0;
    s[t] = v;
    __syncthreads();
    for (int off = 1; off < 128; off <<= 1) {
        int x = (t >= off) ? s[t - off] : 0;
        __syncthreads();
        s[t] += x;
        __syncthreads();
    }
    if (t < nb) bscan[t] = s[t] - v;  // exclusive
    if (t == 0) rowptr[n] = E;
}

__global__ void scan_final(const int* __restrict__ cnt, const int* __restrict__ bscan,
                           int* __restrict__ rowptr, int n) {
    __shared__ int tsum[256];
    int t = threadIdx.x;
    int base = blockIdx.x * 1024 + t * 4;
    int v[4];
#pragma unroll
    for (int i = 0; i < 4; ++i) {
        int idx = base + i;
        v[i] = (idx < n) ? cnt[idx] : 0;
    }
    int tot = v[0] + v[1] + v[2] + v[3];
    tsum[t] = tot;
    __syncthreads();
    for (int off = 1; off < 256; off <<= 1) {
        int x = (t >= off) ? tsum[t - off] : 0;
        __syncthreads();
        tsum[t] += x;
        __syncthreads();
    }
    int run = tsum[t] - tot + bscan[blockIdx.x];  // exclusive offset for this thread
#pragma unroll
    for (int i = 0; i < 4; ++i) {
        int idx = base + i;
        if (idx < n) rowptr[idx] = run;
        run += v[i];
    }
}

__global__ void scatter_edges(const int* __restrict__ row, const int* __restrict__ col,
                              const float* __restrict__ vals, int* __restrict__ cursor,
                              int* __restrict__ scol, float* __restrict__ sval, int E) {
    for (int e = blockIdx.x * blockDim.x + threadIdx.x; e < E; e += gridDim.x * blockDim.x) {
        int r = row[e];
        int p = atomicAdd(&cursor[r], 1);
        scol[p] = col[e];
        sval[p] = vals[e];
    }
}

// ---------------- f32 GEMM: C[M,N] = A[M,K] @ B[K,N] ----------------
// block tile 64x128, 256 threads, thread micro-tile 8 rows x 4 cols.
// grid: (ceil(M/64), N/128). K % 16 == 0, N % 128 == 0.
__global__ __launch_bounds__(256) void gemm_f32(const float* __restrict__ A,
                                                const float* __restrict__ B,
                                                float* __restrict__ C,
                                                int M, int N, int K) {
    __shared__ float As[16][68];   // [k][row], pad 68 keeps float4 alignment + spreads banks
    __shared__ float Bs[16][128];  // [k][col]
    int t = threadIdx.x;
    int tr = t >> 5;    // 0..7  -> row group (8 consecutive rows)
    int tc = t & 31;    // 0..31 -> col group (4 consecutive cols)
    int rbase = blockIdx.x * 64;
    int cb = blockIdx.y * 128;

    float acc[8][4];
#pragma unroll
    for (int i = 0; i < 8; ++i)
#pragma unroll
        for (int j = 0; j < 4; ++j) acc[i][j] = 0.f;

    int arow = t >> 2;        // 0..63
    int akq = (t & 3) * 4;    // 0,4,8,12

    for (int kt = 0; kt < K; kt += 16) {
        // A tile: 64 rows x 16 k, one float4 per thread, stored transposed
        float4 av = make_float4(0.f, 0.f, 0.f, 0.f);
        if (rbase + arow < M)
            av = *(const float4*)&A[(size_t)(rbase + arow) * K + kt + akq];
        As[akq + 0][arow] = av.x;
        As[akq + 1][arow] = av.y;
        As[akq + 2][arow] = av.z;
        As[akq + 3][arow] = av.w;
        // B tile: 16 k x 128 cols, two float4 per thread
        {
            int s0 = t;
            int k0 = s0 >> 5, c0 = (s0 & 31) * 4;
            *(float4*)&Bs[k0][c0] = *(const float4*)&B[(size_t)(kt + k0) * N + cb + c0];
            int s1 = t + 256;
            int k1 = s1 >> 5, c1 = (s1 & 31) * 4;
            *(float4*)&Bs[k1][c1] = *(const float4*)&B[(size_t)(kt + k1) * N + cb + c1];
        }
        __syncthreads();
#pragma unroll
        for (int kk = 0; kk < 16; ++kk) {
            float4 a0 = *(const float4*)&As[kk][tr * 8];
            float4 a1 = *(const float4*)&As[kk][tr * 8 + 4];
            float4 b = *(const float4*)&Bs[kk][tc * 4];
            float a[8] = {a0.x, a0.y, a0.z, a0.w, a1.x, a1.y, a1.z, a1.w};
#pragma unroll
            for (int i = 0; i < 8; ++i) {
                acc[i][0] += a[i] * b.x;
                acc[i][1] += a[i] * b.y;
                acc[i][2] += a[i] * b.z;
                acc[i][3] += a[i] * b.w;
            }
        }
        __syncthreads();
    }
#pragma unroll
    for (int i = 0; i < 8; ++i) {
        int r = rbase + tr * 8 + i;
        if (r < M)
            *(float4*)&C[(size_t)r * N + cb + tc * 4] =
                make_float4(acc[i][0], acc[i][1], acc[i][2], acc[i][3]);
    }
}

// ---------------- SpMM d=128: out[r] = sum_e sval[e] * z[idx(scol[e])] ----------------
// 256 threads = 8 rows per block, 32 lanes per row, float4 per lane.
__global__ __launch_bounds__(256) void spmm128(const int* __restrict__ rowptr,
                                               const int* __restrict__ scol,
                                               const float* __restrict__ sval,
                                               const float* __restrict__ z,
                                               float* __restrict__ out,
                                               const int* __restrict__ perm, int n) {
    int t = threadIdx.x;
    int r = blockIdx.x * 8 + (t >> 5);
    if (r >= n) return;
    int lane4 = (t & 31) * 4;
    int s = rowptr[r], e1 = rowptr[r + 1];
    float4 acc = make_float4(0.f, 0.f, 0.f, 0.f);
    for (int e = s; e < e1; ++e) {
        int c = scol[e];
        if (perm) c = perm[c];
        float v = sval[e];
        float4 zv = *(const float4*)&z[(size_t)c * 128 + lane4];
        acc.x += v * zv.x;
        acc.y += v * zv.y;
        acc.z += v * zv.z;
        acc.w += v * zv.w;
    }
    *(float4*)&out[(size_t)r * 128 + lane4] = acc;
}

// ---------------- launch ----------------

extern "C" void kernel_launch(void* const* d_in, const int* in_sizes, int n_in,
                              void* d_out, int out_size, void* d_ws, size_t ws_size,
                              hipStream_t stream) {
    const float* x     = (const float*)d_in[0];
    const float* W_enc = (const float*)d_in[1];
    const float* W_dec = (const float*)d_in[2];
    const float* vals  = (const float*)d_in[3];
    const int*   row   = (const int*)d_in[4];
    const int*   col   = (const int*)d_in[5];
    const int*   perm  = (const int*)d_in[6];
    const int n = in_sizes[6];
    const int E = in_sizes[4];
    const int IN = 512, L = 128;

    float* out0  = (float*)d_out;                 // [n,512]
    float* outh  = out0 + (size_t)n * IN;         // [n,128]
    float* outha = outh + (size_t)n * L;          // [n,128]

    char* w = (char*)d_ws;
    auto alloc = [&](size_t bytes) -> char* {
        char* p = w;
        w += (bytes + 255) & ~(size_t)255;
        return p;
    };
    float* z1     = (float*)alloc((size_t)n * L * 4);
    float* g      = (float*)alloc((size_t)n * L * 4);
    int*   scol   = (int*)alloc((size_t)E * 4);
    float* sval   = (float*)alloc((size_t)E * 4);
    int*   rowptr = (int*)alloc((size_t)(n + 1) * 4);
    int*   cursor = (int*)alloc((size_t)n * 4);
    int*   cnt    = (int*)alloc((size_t)n * 4);
    int*   bsum   = (int*)alloc(128 * 4);
    int*   bscan  = (int*)alloc(128 * 4);

    const int nb = (n + 1023) / 1024;  // 98 for n=100000 (<=128 required)

    hipLaunchKernelGGL(zero_i32, dim3((n + 255) / 256), dim3(256), 0, stream, cnt, n);
    hipLaunchKernelGGL(hist_rows, dim3(2048), dim3(256), 0, stream, row, cnt, E);
    hipLaunchKernelGGL(scan_partial, dim3(nb), dim3(256), 0, stream, cnt, bsum, n);
    hipLaunchKernelGGL(scan_bsum, dim3(1), dim3(128), 0, stream, bsum, bscan, nb, rowptr, n, E);
    hipLaunchKernelGGL(scan_final, dim3(nb), dim3(256), 0, stream, cnt, bscan, rowptr, n);
    hipLaunchKernelGGL(copy_i32, dim3((n + 255) / 256), dim3(256), 0, stream, rowptr, cursor, n);
    hipLaunchKernelGGL(scatter_edges, dim3(2048), dim3(256), 0, stream,
                       row, col, vals, cursor, scol, sval, E);

    // z1 = x @ W_enc   [n,512]@[512,128]
    hipLaunchKernelGGL(gemm_f32, dim3((n + 63) / 64, 1), dim3(256), 0, stream,
                       x, W_enc, z1, n, L, IN);
    // h = adj @ z1
    hipLaunchKernelGGL(spmm128, dim3((n + 7) / 8), dim3(256), 0, stream,
                       rowptr, scol, sval, z1, outh, (const int*)nullptr, n);
    // h_a = adj @ z1[perm]
    hipLaunchKernelGGL(spmm128, dim3((n + 7) / 8), dim3(256), 0, stream,
                       rowptr, scol, sval, z1, outha, perm, n);
    // g = adj @ h
    hipLaunchKernelGGL(spmm128, dim3((n + 7) / 8), dim3(256), 0, stream,
                       rowptr, scol, sval, outh, g, (const int*)nullptr, n);
    // out = g @ W_dec  [n,128]@[128,512]
    hipLaunchKernelGGL(gemm_f32, dim3((n + 63) / 64, 4), dim3(256), 0, stream,
                       g, W_dec, out0, n, IN, L);
}

// Round 4
// 1459.583 us; speedup vs baseline: 1.2107x; 1.2107x over previous
//
#include <hip/hip_runtime.h>
#include <hip/hip_bf16.h>

// GraphAutoEncoder: out = (adj@(adj@z1))@W_dec, h = adj@z1, h_a = adj@z1[perm],
// z1 = x@W_enc.  Edges counting-sorted by row once (packed 8B records);
// SpMM gather tables stored bf16 (halves gather traffic, L3-friendlier).

typedef unsigned int uint;
typedef unsigned short ushort;

// ---- bf16 helpers ----
__device__ inline ushort f2bf(float f) {            // RNE round f32 -> bf16
    uint u = __float_as_uint(f);
    return (ushort)((u + 0x7FFFu + ((u >> 16) & 1u)) >> 16);
}
__device__ inline float bflo(uint u) { return __uint_as_float(u << 16); }
__device__ inline float bfhi(uint u) { return __uint_as_float(u & 0xFFFF0000u); }

// ---------------- utility kernels ----------------

__global__ void zero_i32(int* __restrict__ p, int n) {
    int i = blockIdx.x * blockDim.x + threadIdx.x;
    if (i < n) p[i] = 0;
}

__global__ void copy_i32(const int* __restrict__ src, int* __restrict__ dst, int n) {
    int i = blockIdx.x * blockDim.x + threadIdx.x;
    if (i < n) dst[i] = src[i];
}

__global__ void hist_rows(const int* __restrict__ row, int* __restrict__ cnt, int E) {
    for (int e = blockIdx.x * blockDim.x + threadIdx.x; e < E; e += gridDim.x * blockDim.x)
        atomicAdd(&cnt[row[e]], 1);
}

// chunk = 1024 elements per block (256 threads x 4)
__global__ void scan_partial(const int* __restrict__ cnt, int* __restrict__ bsum, int n) {
    __shared__ int red[256];
    int t = threadIdx.x;
    int base = blockIdx.x * 1024 + t * 4;
    int s = 0;
#pragma unroll
    for (int i = 0; i < 4; ++i) {
        int idx = base + i;
        if (idx < n) s += cnt[idx];
    }
    red[t] = s;
    __syncthreads();
    for (int off = 128; off > 0; off >>= 1) {
        if (t < off) red[t] += red[t + off];
        __syncthreads();
    }
    if (t == 0) bsum[blockIdx.x] = red[0];
}

// single block, 128 threads; nb <= 128
__global__ void scan_bsum(const int* __restrict__ bsum, int* __restrict__ bscan,
                          int nb, int* __restrict__ rowptr, int n, int E) {
    __shared__ int s[128];
    int t = threadIdx.x;
    int v = (t < nb) ? bsum[t] : 0;
    s[t] = v;
    __syncthreads();
    for (int off = 1; off < 128; off <<= 1) {
        int x = (t >= off) ? s[t - off] : 0;
        __syncthreads();
        s[t] += x;
        __syncthreads();
    }
    if (t < nb) bscan[t] = s[t] - v;  // exclusive
    if (t == 0) rowptr[n] = E;
}

__global__ void scan_final(const int* __restrict__ cnt, const int* __restrict__ bscan,
                           int* __restrict__ rowptr, int n) {
    __shared__ int tsum[256];
    int t = threadIdx.x;
    int base = blockIdx.x * 1024 + t * 4;
    int v[4];
#pragma unroll
    for (int i = 0; i < 4; ++i) {
        int idx = base + i;
        v[i] = (idx < n) ? cnt[idx] : 0;
    }
    int tot = v[0] + v[1] + v[2] + v[3];
    tsum[t] = tot;
    __syncthreads();
    for (int off = 1; off < 256; off <<= 1) {
        int x = (t >= off) ? tsum[t - off] : 0;
        __syncthreads();
        tsum[t] += x;
        __syncthreads();
    }
    int run = tsum[t] - tot + bscan[blockIdx.x];
#pragma unroll
    for (int i = 0; i < 4; ++i) {
        int idx = base + i;
        if (idx < n) rowptr[idx] = run;
        run += v[i];
    }
}

// packed (col, val) record: one 8B store per edge instead of two 4B stores
__global__ void scatter_edges(const int* __restrict__ row, const int* __restrict__ col,
                              const float* __restrict__ vals, int* __restrict__ cursor,
                              uint2* __restrict__ ep, int E) {
    for (int e = blockIdx.x * blockDim.x + threadIdx.x; e < E; e += gridDim.x * blockDim.x) {
        int r = row[e];
        int p = atomicAdd(&cursor[r], 1);
        ep[p] = make_uint2((uint)col[e], __float_as_uint(vals[e]));
    }
}

// ---------------- f32 GEMM: C[M,N] = A[M,K] @ B[K,N] ----------------
// block tile 64x128, 256 threads, micro-tile 8x4. If Cb != null, store bf16.
__global__ __launch_bounds__(256) void gemm_f32(const float* __restrict__ A,
                                                const float* __restrict__ B,
                                                float* __restrict__ Cf,
                                                ushort* __restrict__ Cb,
                                                int M, int N, int K) {
    __shared__ float As[16][68];
    __shared__ float Bs[16][128];
    int t = threadIdx.x;
    int tr = t >> 5;
    int tc = t & 31;
    int rbase = blockIdx.x * 64;
    int cb = blockIdx.y * 128;

    float acc[8][4];
#pragma unroll
    for (int i = 0; i < 8; ++i)
#pragma unroll
        for (int j = 0; j < 4; ++j) acc[i][j] = 0.f;

    int arow = t >> 2;
    int akq = (t & 3) * 4;

    for (int kt = 0; kt < K; kt += 16) {
        float4 av = make_float4(0.f, 0.f, 0.f, 0.f);
        if (rbase + arow < M)
            av = *(const float4*)&A[(size_t)(rbase + arow) * K + kt + akq];
        As[akq + 0][arow] = av.x;
        As[akq + 1][arow] = av.y;
        As[akq + 2][arow] = av.z;
        As[akq + 3][arow] = av.w;
        {
            int s0 = t;
            int k0 = s0 >> 5, c0 = (s0 & 31) * 4;
            *(float4*)&Bs[k0][c0] = *(const float4*)&B[(size_t)(kt + k0) * N + cb + c0];
            int s1 = t + 256;
            int k1 = s1 >> 5, c1 = (s1 & 31) * 4;
            *(float4*)&Bs[k1][c1] = *(const float4*)&B[(size_t)(kt + k1) * N + cb + c1];
        }
        __syncthreads();
#pragma unroll
        for (int kk = 0; kk < 16; ++kk) {
            float4 a0 = *(const float4*)&As[kk][tr * 8];
            float4 a1 = *(const float4*)&As[kk][tr * 8 + 4];
            float4 b = *(const float4*)&Bs[kk][tc * 4];
            float a[8] = {a0.x, a0.y, a0.z, a0.w, a1.x, a1.y, a1.z, a1.w};
#pragma unroll
            for (int i = 0; i < 8; ++i) {
                acc[i][0] += a[i] * b.x;
                acc[i][1] += a[i] * b.y;
                acc[i][2] += a[i] * b.z;
                acc[i][3] += a[i] * b.w;
            }
        }
        __syncthreads();
    }
#pragma unroll
    for (int i = 0; i < 8; ++i) {
        int r = rbase + tr * 8 + i;
        if (r < M) {
            if (Cb) {
                ushort4 o;
                o.x = f2bf(acc[i][0]);
                o.y = f2bf(acc[i][1]);
                o.z = f2bf(acc[i][2]);
                o.w = f2bf(acc[i][3]);
                *(ushort4*)&Cb[(size_t)r * N + cb + tc * 4] = o;
            } else {
                *(float4*)&Cf[(size_t)r * N + cb + tc * 4] =
                    make_float4(acc[i][0], acc[i][1], acc[i][2], acc[i][3]);
            }
        }
    }
}

// ---------------- SpMM d=128, bf16 table ----------------
// 16 lanes per row, 8 features per lane (one uint4 = 8 bf16 per gather).
// Fused variant: out_h[r] = sum v*zb[col], out_ha[r] = sum v*zb[perm[col]],
// also emits hb = bf16(out_h).
__global__ __launch_bounds__(256) void spmm_fused(const int* __restrict__ rowptr,
                                                  const uint2* __restrict__ ep,
                                                  const ushort* __restrict__ zb,
                                                  const int* __restrict__ perm,
                                                  float* __restrict__ outh,
                                                  float* __restrict__ outha,
                                                  ushort* __restrict__ hb, int n) {
    int t = threadIdx.x;
    int r = blockIdx.x * 16 + (t >> 4);
    if (r >= n) return;
    int lo = (t & 15) * 8;
    int s = rowptr[r], e1 = rowptr[r + 1];
    float ah[8] = {0, 0, 0, 0, 0, 0, 0, 0};
    float aa[8] = {0, 0, 0, 0, 0, 0, 0, 0};
    for (int e = s; e < e1; ++e) {
        uint2 ed = ep[e];
        int c = (int)ed.x;
        float v = __uint_as_float(ed.y);
        int c2 = perm[c];
        uint4 za = *(const uint4*)&zb[(size_t)c * 128 + lo];
        uint4 zp = *(const uint4*)&zb[(size_t)c2 * 128 + lo];
        ah[0] += v * bflo(za.x); ah[1] += v * bfhi(za.x);
        ah[2] += v * bflo(za.y); ah[3] += v * bfhi(za.y);
        ah[4] += v * bflo(za.z); ah[5] += v * bfhi(za.z);
        ah[6] += v * bflo(za.w); ah[7] += v * bfhi(za.w);
        aa[0] += v * bflo(zp.x); aa[1] += v * bfhi(zp.x);
        aa[2] += v * bflo(zp.y); aa[3] += v * bfhi(zp.y);
        aa[4] += v * bflo(zp.z); aa[5] += v * bfhi(zp.z);
        aa[6] += v * bflo(zp.w); aa[7] += v * bfhi(zp.w);
    }
    size_t o = (size_t)r * 128 + lo;
    *(float4*)&outh[o]     = make_float4(ah[0], ah[1], ah[2], ah[3]);
    *(float4*)&outh[o + 4] = make_float4(ah[4], ah[5], ah[6], ah[7]);
    *(float4*)&outha[o]     = make_float4(aa[0], aa[1], aa[2], aa[3]);
    *(float4*)&outha[o + 4] = make_float4(aa[4], aa[5], aa[6], aa[7]);
    uint4 hp;
    hp.x = (uint)f2bf(ah[0]) | ((uint)f2bf(ah[1]) << 16);
    hp.y = (uint)f2bf(ah[2]) | ((uint)f2bf(ah[3]) << 16);
    hp.z = (uint)f2bf(ah[4]) | ((uint)f2bf(ah[5]) << 16);
    hp.w = (uint)f2bf(ah[6]) | ((uint)f2bf(ah[7]) << 16);
    *(uint4*)&hb[o] = hp;
}

__global__ __launch_bounds__(256) void spmm_single(const int* __restrict__ rowptr,
                                                   const uint2* __restrict__ ep,
                                                   const ushort* __restrict__ zb,
                                                   float* __restrict__ out, int n) {
    int t = threadIdx.x;
    int r = blockIdx.x * 16 + (t >> 4);
    if (r >= n) return;
    int lo = (t & 15) * 8;
    int s = rowptr[r], e1 = rowptr[r + 1];
    float ah[8] = {0, 0, 0, 0, 0, 0, 0, 0};
    for (int e = s; e < e1; ++e) {
        uint2 ed = ep[e];
        int c = (int)ed.x;
        float v = __uint_as_float(ed.y);
        uint4 za = *(const uint4*)&zb[(size_t)c * 128 + lo];
        ah[0] += v * bflo(za.x); ah[1] += v * bfhi(za.x);
        ah[2] += v * bflo(za.y); ah[3] += v * bfhi(za.y);
        ah[4] += v * bflo(za.z); ah[5] += v * bfhi(za.z);
        ah[6] += v * bflo(za.w); ah[7] += v * bfhi(za.w);
    }
    size_t o = (size_t)r * 128 + lo;
    *(float4*)&out[o]     = make_float4(ah[0], ah[1], ah[2], ah[3]);
    *(float4*)&out[o + 4] = make_float4(ah[4], ah[5], ah[6], ah[7]);
}

// ---------------- launch ----------------

extern "C" void kernel_launch(void* const* d_in, const int* in_sizes, int n_in,
                              void* d_out, int out_size, void* d_ws, size_t ws_size,
                              hipStream_t stream) {
    const float* x     = (const float*)d_in[0];
    const float* W_enc = (const float*)d_in[1];
    const float* W_dec = (const float*)d_in[2];
    const float* vals  = (const float*)d_in[3];
    const int*   row   = (const int*)d_in[4];
    const int*   col   = (const int*)d_in[5];
    const int*   perm  = (const int*)d_in[6];
    const int n = in_sizes[6];
    const int E = in_sizes[4];
    const int IN = 512, L = 128;

    float* out0  = (float*)d_out;                 // [n,512]
    float* outh  = out0 + (size_t)n * IN;         // [n,128] f32
    float* outha = outh + (size_t)n * L;          // [n,128] f32

    char* w = (char*)d_ws;
    auto alloc = [&](size_t bytes) -> char* {
        char* p = w;
        w += (bytes + 255) & ~(size_t)255;
        return p;
    };
    ushort* z1b   = (ushort*)alloc((size_t)n * L * 2);   // bf16 z1
    ushort* hb    = (ushort*)alloc((size_t)n * L * 2);   // bf16 h
    float*  g     = (float*)alloc((size_t)n * L * 4);    // f32 adj@h
    uint2*  ep    = (uint2*)alloc((size_t)E * 8);        // packed (col,val)
    int*   rowptr = (int*)alloc((size_t)(n + 1) * 4);
    int*   cursor = (int*)alloc((size_t)n * 4);
    int*   cnt    = (int*)alloc((size_t)n * 4);
    int*   bsum   = (int*)alloc(128 * 4);
    int*   bscan  = (int*)alloc(128 * 4);

    const int nb = (n + 1023) / 1024;  // 98 for n=100000 (<=128 required)

    hipLaunchKernelGGL(zero_i32, dim3((n + 255) / 256), dim3(256), 0, stream, cnt, n);
    hipLaunchKernelGGL(hist_rows, dim3(2048), dim3(256), 0, stream, row, cnt, E);
    hipLaunchKernelGGL(scan_partial, dim3(nb), dim3(256), 0, stream, cnt, bsum, n);
    hipLaunchKernelGGL(scan_bsum, dim3(1), dim3(128), 0, stream, bsum, bscan, nb, rowptr, n, E);
    hipLaunchKernelGGL(scan_final, dim3(nb), dim3(256), 0, stream, cnt, bscan, rowptr, n);
    hipLaunchKernelGGL(copy_i32, dim3((n + 255) / 256), dim3(256), 0, stream, rowptr, cursor, n);
    hipLaunchKernelGGL(scatter_edges, dim3(2048), dim3(256), 0, stream,
                       row, col, vals, cursor, ep, E);

    // z1b = bf16(x @ W_enc)   [n,512]@[512,128]
    hipLaunchKernelGGL(gemm_f32, dim3((n + 63) / 64, 1), dim3(256), 0, stream,
                       x, W_enc, (float*)nullptr, z1b, n, L, IN);
    // h = adj @ z1 (f32 out + bf16 hb), h_a = adj @ z1[perm]  — fused
    hipLaunchKernelGGL(spmm_fused, dim3((n + 15) / 16), dim3(256), 0, stream,
                       rowptr, ep, z1b, perm, outh, outha, hb, n);
    // g = adj @ h
    hipLaunchKernelGGL(spmm_single, dim3((n + 15) / 16), dim3(256), 0, stream,
                       rowptr, ep, hb, g, n);
    // out = g @ W_dec  [n,128]@[128,512]
    hipLaunchKernelGGL(gemm_f32, dim3((n + 63) / 64, 4), dim3(256), 0, stream,
                       g, W_dec, out0, (ushort*)nullptr, n, IN, L);
}